// Round 8
// baseline (430.129 us; speedup 1.0000x reference)
//
#include <hip/hip_runtime.h>
#include <hip/hip_bf16.h>

#define TOKENS 4096
#define HDIM 1024
#define NEXP 16
#define BM 128
#define BN 128
#define BK 64
#define NBLK 512
#define NTHR 512

typedef __bf16 bf16x8 __attribute__((ext_vector_type(8)));
typedef __bf16 bf16x4 __attribute__((ext_vector_type(4)));
typedef float f32x4 __attribute__((ext_vector_type(4)));

__device__ inline void gload16(const void* g, const void* l) {
  __builtin_amdgcn_global_load_lds((const __attribute__((address_space(1))) void*)g,
                                   (__attribute__((address_space(3))) void*)l, 16, 0, 0);
}

// Manual grid barrier. All NBLK=512 blocks co-resident (worst case 2 blocks/CU x 256 CU).
__device__ inline void grid_barrier(int* bar, int gen) {
  __threadfence();
  __syncthreads();
  if (threadIdx.x == 0) {
    if (atomicAdd(&bar[0], 1) == NBLK - 1) {
      atomicExch(&bar[0], 0);
      __threadfence();
      atomicAdd(&bar[1], 1);
    } else {
      while (atomicAdd(&bar[1], 0) < gen) __builtin_amdgcn_s_sleep(8);
    }
    __threadfence();
  }
  __syncthreads();
}

__global__ __launch_bounds__(NTHR, 4) void moe_fused(
    const float* __restrict__ tokens, const float* __restrict__ gate_w,
    const float* __restrict__ expert_w, const float* __restrict__ expert_b,
    float* __restrict__ out, int* __restrict__ bar,
    int* __restrict__ tok_idx, float* __restrict__ tok_w,
    int* __restrict__ counts, int* __restrict__ list_tok, float* __restrict__ list_w,
    __bf16* __restrict__ w_bf, __bf16* __restrict__ tok_bf) {
  __shared__ __bf16 lds[(BM + BN) * BK];   // 32 KB, single buffer (m97 shape)
  __shared__ int s_cur;

  int tid = threadIdx.x;
  int lane = tid & 63;
  int wv = tid >> 6;   // 0..7
  int bid = blockIdx.x;

  // ================= P0: zero out + fp32->bf16 W conversion =================
  {
    size_t gtid = (size_t)bid * NTHR + tid;
    size_t gs = (size_t)NBLK * NTHR;   // 262144
    float4* out4 = (float4*)out;
    for (size_t i = gtid; i < (size_t)TOKENS * HDIM / 4; i += gs)
      out4[i] = float4{0.f, 0.f, 0.f, 0.f};
    const float4* w4 = (const float4*)expert_w;
    bf16x8* wb8 = (bf16x8*)w_bf;
    for (size_t i = gtid; i < (size_t)NEXP * HDIM * HDIM / 8; i += gs) {
      float4 a = w4[2 * i], b = w4[2 * i + 1];
      bf16x8 v;
      v[0] = (__bf16)a.x; v[1] = (__bf16)a.y; v[2] = (__bf16)a.z; v[3] = (__bf16)a.w;
      v[4] = (__bf16)b.x; v[5] = (__bf16)b.y; v[6] = (__bf16)b.z; v[7] = (__bf16)b.w;
      wb8[i] = v;
    }
  }

  // ================= P1: gate (fp32-exact) + fused token bf16 cvt =================
  {
    int token = bid * 8 + wv;   // 512*8 = 4096 = TOKENS exactly
    const float* trow = tokens + (size_t)token * HDIM;
    float4 tv[4];
#pragma unroll
    for (int s = 0; s < 4; ++s) tv[s] = *(const float4*)(trow + s * 256 + lane * 4);

    // fused fp32->bf16 token conversion (row already in registers)
#pragma unroll
    for (int s = 0; s < 4; ++s) {
      bf16x4 v;
      v[0] = (__bf16)tv[s].x; v[1] = (__bf16)tv[s].y;
      v[2] = (__bf16)tv[s].z; v[3] = (__bf16)tv[s].w;
      *(bf16x4*)(tok_bf + (size_t)token * HDIM + s * 256 + lane * 4) = v;
    }

    float lg[NEXP];
#pragma unroll
    for (int e = 0; e < NEXP; ++e) {
      float d = 0.f;
#pragma unroll
      for (int s = 0; s < 4; ++s) {
        float4 g = *(const float4*)(gate_w + e * HDIM + s * 256 + lane * 4);
        d += tv[s].x * g.x + tv[s].y * g.y + tv[s].z * g.z + tv[s].w * g.w;
      }
#pragma unroll
      for (int off = 32; off; off >>= 1) d += __shfl_xor(d, off);
      lg[e] = d;
    }
    int i0 = 0; float b0 = lg[0];
#pragma unroll
    for (int e = 1; e < NEXP; ++e) if (lg[e] > b0) { b0 = lg[e]; i0 = e; }
    int i1 = -1; float b1 = -1e30f;
#pragma unroll
    for (int e = 0; e < NEXP; ++e) {
      if (e == i0) continue;
      if (lg[e] > b1) { b1 = lg[e]; i1 = e; }
    }
    float s = 0.f;
#pragma unroll
    for (int e = 0; e < NEXP; ++e) s += expf(lg[e] - b0);
    if (lane == 0) {
      tok_idx[token * 2 + 0] = i0;
      tok_idx[token * 2 + 1] = i1;
      tok_w[token * 2 + 0] = 1.0f / s;
      tok_w[token * 2 + 1] = expf(b1 - b0) / s;
    }
  }

  grid_barrier(bar, 1);

  // ================= P2: per-expert lists (blocks 0-15) =================
  if (bid < NEXP) {
    if (tid == 0) s_cur = 0;
    __syncthreads();
    for (int s = tid; s < TOKENS * 2; s += NTHR) {
      if (tok_idx[s] == bid) {
        int pos = atomicAdd(&s_cur, 1);
        list_tok[bid * TOKENS + pos] = s >> 1;
        list_w[bid * TOKENS + pos] = tok_w[s];
      }
    }
    __syncthreads();
    if (tid == 0) counts[bid] = s_cur;
  }

  grid_barrier(bar, 2);

  // ================= P3: grouped GEMM, single-buffer, grid-stride tiles =================
  {
    // total tiles = (sum over e of ceil(cnt/BM)) * 8 n-tiles
    int lr = lane & 15;
    int lk = lane >> 4;
    int wr = (wv >> 2) * 64;   // 0 / 64
    int wc = (wv & 3) * 32;    // 0 / 32 / 64 / 96

    int dstb[2];
#pragma unroll
    for (int i = 0; i < 2; ++i) dstb[i] = (wv * 2 + i) * 512;

    int aoffr[2][4], boffr[2][2];
#pragma unroll
    for (int kk = 0; kk < 2; ++kk) {
#pragma unroll
      for (int m = 0; m < 4; ++m) {
        int r = wr + m * 16 + lr;
        aoffr[kk][m] = r * BK + (((kk * 4 + lk) ^ (r & 7)) * 8);
      }
#pragma unroll
      for (int n = 0; n < 2; ++n) {
        int d = wc + n * 16 + lr;
        boffr[kk][n] = BM * BK + d * BK + (((kk * 4 + lk) ^ (d & 7)) * 8);
      }
    }

    // npairs from counts (same on every block)
    int cnts[NEXP];
    int npairs = 0;
#pragma unroll
    for (int ee = 0; ee < NEXP; ++ee) {
      cnts[ee] = counts[ee];
      npairs += (cnts[ee] + BM - 1) >> 7;
    }
    int n_tiles = npairs * 8;

    for (int t = bid; t < n_tiles; t += NBLK) {
      int pair = t >> 3, nt = t & 7;
      int e = 0, mt = pair, acc_p = 0;
#pragma unroll
      for (int ee = 0; ee < NEXP; ++ee) {
        int tc = (cnts[ee] + BM - 1) >> 7;
        if (pair >= acc_p && pair < acc_p + tc) { e = ee; mt = pair - acc_p; }
        acc_p += tc;
      }
      int cnt = cnts[e];
      int lbase = e * TOKENS;

      const __bf16* aptr[2];
      const __bf16* bptr[2];
#pragma unroll
      for (int i = 0; i < 2; ++i) {
        int c = (wv * 2 + i) * 64 + lane;
        int r = c >> 3, kc = c & 7;
        int gr = mt * BM + r;
        int tok = list_tok[lbase + min(gr, cnt - 1)];
        aptr[i] = tok_bf + (size_t)tok * HDIM + (kc ^ (r & 7)) * 8;
        int d = nt * BN + r;
        bptr[i] = w_bf + ((size_t)e * HDIM + d) * HDIM + (kc ^ (r & 7)) * 8;
      }

      f32x4 acc[4][2] = {};

      for (int kb = 0; kb < HDIM / BK; ++kb) {
        int ko = kb * BK;
#pragma unroll
        for (int i = 0; i < 2; ++i) gload16(aptr[i] + ko, &lds[dstb[i]]);
#pragma unroll
        for (int i = 0; i < 2; ++i) gload16(bptr[i] + ko, &lds[BM * BK + dstb[i]]);
        __syncthreads();   // vmcnt drained -> LDS ready

        bf16x8 af[2][4], bfr[2][2];
#pragma unroll
        for (int kk = 0; kk < 2; ++kk) {
#pragma unroll
          for (int m = 0; m < 4; ++m) af[kk][m] = *(const bf16x8*)(&lds[aoffr[kk][m]]);
#pragma unroll
          for (int n = 0; n < 2; ++n) bfr[kk][n] = *(const bf16x8*)(&lds[boffr[kk][n]]);
        }
#pragma unroll
        for (int kk = 0; kk < 2; ++kk)
#pragma unroll
          for (int m = 0; m < 4; ++m)
#pragma unroll
            for (int n = 0; n < 2; ++n)
              acc[m][n] = __builtin_amdgcn_mfma_f32_16x16x32_bf16(af[kk][m], bfr[kk][n], acc[m][n], 0, 0, 0);

        __syncthreads();   // all reads done before next restage
      }

      // epilogue: C/D layout col = lane&15, row = (lane>>4)*4 + j
#pragma unroll
      for (int m = 0; m < 4; ++m) {
#pragma unroll
        for (int j = 0; j < 4; ++j) {
          int rloc = wr + m * 16 + lk * 4 + j;
          int grow = mt * BM + rloc;
          if (grow < cnt) {
            int tok = list_tok[lbase + grow];
            float gw = list_w[lbase + grow];
            float* orow = out + (size_t)tok * HDIM + nt * BN + wc;
            const float* brow = expert_b + e * HDIM + nt * BN + wc;
#pragma unroll
            for (int n = 0; n < 2; ++n) {
              int dc = n * 16 + lr;
              float v = acc[m][n][j] + brow[dc];
              atomicAdd(orow + dc, fmaxf(v, 0.f) * gw);
            }
          }
        }
      }
    }
  }
}

extern "C" void kernel_launch(void* const* d_in, const int* in_sizes, int n_in,
                              void* d_out, int out_size, void* d_ws, size_t ws_size,
                              hipStream_t stream) {
  const float* tokens = (const float*)d_in[0];
  const float* gate_w = (const float*)d_in[1];
  const float* expert_w = (const float*)d_in[2];
  const float* expert_b = (const float*)d_in[3];
  float* out = (float*)d_out;

  int* bar = (int*)d_ws;                               // 16 (use 2)
  int* counts = bar + 16;                              // 16
  int* tok_idx = counts + 16;                          // 8192
  float* tok_w = (float*)(tok_idx + TOKENS * 2);       // 8192
  int* list_tok = (int*)(tok_w + TOKENS * 2);          // 65536
  float* list_w = (float*)(list_tok + NEXP * TOKENS);  // 65536
  size_t head = (size_t)(list_w + NEXP * TOKENS) - (size_t)d_ws;
  head = (head + 255) & ~(size_t)255;
  __bf16* w_bf = (__bf16*)((char*)d_ws + head);        // 32 MB
  __bf16* tok_bf = w_bf + (size_t)NEXP * HDIM * HDIM;  // 8 MB

  hipMemsetAsync(bar, 0, 2 * sizeof(int), stream);

  moe_fused<<<NBLK, NTHR, 0, stream>>>(tokens, gate_w, expert_w, expert_b, out, bar,
                                       tok_idx, tok_w, counts, list_tok, list_w,
                                       w_bf, tok_bf);
}

// Round 9
// 200.278 us; speedup vs baseline: 2.1477x; 2.1477x over previous
//
#include <hip/hip_runtime.h>
#include <hip/hip_bf16.h>

#define TOKENS 4096
#define HDIM 1024
#define NEXP 16
#define BM 128
#define BN 64
#define BK 64
#define MAXP 80                 // worst-case sum of ceil(cnt_e/BM) = 64+15 -> 80
#define MAXT (MAXP * 16)        // 1280

typedef __bf16 bf16x8 __attribute__((ext_vector_type(8)));
typedef __bf16 bf16x4 __attribute__((ext_vector_type(4)));
typedef float f32x4 __attribute__((ext_vector_type(4)));

__device__ inline void gload16(const void* g, const void* l) {
  __builtin_amdgcn_global_load_lds((const __attribute__((address_space(1))) void*)g,
                                   (__attribute__((address_space(3))) void*)l, 16, 0, 0);
}

// ---------------- fp32 -> bf16 weight conversion, 8 elems/thread ----------------
__global__ __launch_bounds__(256) void cvt_kernel(const float* __restrict__ src,
                                                  __bf16* __restrict__ dst) {
  int i = blockIdx.x * 256 + threadIdx.x;
  float4 a = ((const float4*)src)[i * 2];
  float4 b = ((const float4*)src)[i * 2 + 1];
  bf16x8 v;
  v[0] = (__bf16)a.x; v[1] = (__bf16)a.y; v[2] = (__bf16)a.z; v[3] = (__bf16)a.w;
  v[4] = (__bf16)b.x; v[5] = (__bf16)b.y; v[6] = (__bf16)b.z; v[7] = (__bf16)b.w;
  ((bf16x8*)dst)[i] = v;
}

// ---------------- Gate: fp32-exact logits/softmax/top2 + fused token bf16 cvt ----------------
__global__ __launch_bounds__(256) void gate_kernel(
    const float* __restrict__ tokens, const float* __restrict__ gate_w,
    int* __restrict__ tok_idx, float* __restrict__ tok_w, __bf16* __restrict__ tok_bf) {
  int lane = threadIdx.x & 63;
  int wv = threadIdx.x >> 6;
  int token = blockIdx.x * 4 + wv;
  const float* trow = tokens + (size_t)token * HDIM;

  float4 tv[4];
#pragma unroll
  for (int s = 0; s < 4; ++s) tv[s] = *(const float4*)(trow + s * 256 + lane * 4);

#pragma unroll
  for (int s = 0; s < 4; ++s) {
    bf16x4 v;
    v[0] = (__bf16)tv[s].x; v[1] = (__bf16)tv[s].y;
    v[2] = (__bf16)tv[s].z; v[3] = (__bf16)tv[s].w;
    *(bf16x4*)(tok_bf + (size_t)token * HDIM + s * 256 + lane * 4) = v;
  }

  float lg[NEXP];
#pragma unroll
  for (int e = 0; e < NEXP; ++e) {
    float d = 0.f;
#pragma unroll
    for (int s = 0; s < 4; ++s) {
      float4 g = *(const float4*)(gate_w + e * HDIM + s * 256 + lane * 4);
      d += tv[s].x * g.x + tv[s].y * g.y + tv[s].z * g.z + tv[s].w * g.w;
    }
#pragma unroll
    for (int off = 32; off; off >>= 1) d += __shfl_xor(d, off);
    lg[e] = d;
  }

  int i0 = 0; float b0 = lg[0];
#pragma unroll
  for (int e = 1; e < NEXP; ++e) if (lg[e] > b0) { b0 = lg[e]; i0 = e; }
  int i1 = -1; float b1 = -1e30f;
#pragma unroll
  for (int e = 0; e < NEXP; ++e) {
    if (e == i0) continue;
    if (lg[e] > b1) { b1 = lg[e]; i1 = e; }
  }
  float s = 0.f;
#pragma unroll
  for (int e = 0; e < NEXP; ++e) s += expf(lg[e] - b0);
  if (lane == 0) {
    tok_idx[token * 2 + 0] = i0;
    tok_idx[token * 2 + 1] = i1;
    tok_w[token * 2 + 0] = 1.0f / s;
    tok_w[token * 2 + 1] = expf(b1 - b0) / s;
  }
}

// ---------------- Per-expert list compaction (LDS cursor) ----------------
__global__ __launch_bounds__(1024) void build_lists_kernel(
    const int* __restrict__ tok_idx, const float* __restrict__ tok_w,
    int* __restrict__ counts, int* __restrict__ list_tok, float* __restrict__ list_w) {
  int e = blockIdx.x;
  __shared__ int cur;
  if (threadIdx.x == 0) cur = 0;
  __syncthreads();
  for (int s = threadIdx.x; s < TOKENS * 2; s += 1024) {
    if (tok_idx[s] == e) {
      int pos = atomicAdd(&cur, 1);
      list_tok[e * TOKENS + pos] = s >> 1;
      list_w[e * TOKENS + pos] = tok_w[s];
    }
  }
  __syncthreads();
  if (threadIdx.x == 0) counts[e] = cur;
}

// ---------------- Plan: pair -> (expert, mt) ----------------
__global__ void plan_kernel(const int* __restrict__ counts, int* __restrict__ tiles,
                            int* __restrict__ npg) {
  if (threadIdx.x == 0) {
    int n = 0;
    for (int e = 0; e < NEXP; ++e) {
      int t = (counts[e] + BM - 1) / BM;
      for (int m = 0; m < t; ++m) { tiles[n * 2] = e; tiles[n * 2 + 1] = m; ++n; }
    }
    *npg = n;
  }
}

// ---------------- Grouped GEMM: 8 waves, 128x64 tile, dbuf, XCD-chunked ----------------
// LDS/buf: A[128][64] + B[64][64] bf16 (24 KB); XOR swizzle via pre-swizzled global
// source column (m173): slot (r,kc) holds G(r, kc^(r&7)).
// Tile linearization: tile = nt*npairs + pair. XCD-chunk swizzle (8 | n_tiles):
// consecutive swz in a chunk share the same nt and consecutive (mostly same-expert)
// pairs -> B panel reused within one XCD's L2.
__global__ __launch_bounds__(512, 6) void moe_gemm_kernel(
    const __bf16* __restrict__ tok_bf, const __bf16* __restrict__ w_bf,
    const float* __restrict__ expert_b, const int* __restrict__ counts,
    const int* __restrict__ tiles, const int* __restrict__ npg,
    const int* __restrict__ list_tok, const float* __restrict__ list_w,
    float* __restrict__ out) {
  int npairs = *npg;
  int n_tiles = npairs * 16;
  int bid = blockIdx.x;
  if (bid >= n_tiles) return;
  int chunk = n_tiles >> 3;
  int swz = (bid & 7) * chunk + (bid >> 3);
  int nt = swz / npairs;
  int pair = swz - nt * npairs;
  int e = tiles[pair * 2];
  int mt = tiles[pair * 2 + 1];
  int cnt = counts[e];
  const int lbase = e * TOKENS;

  __shared__ __bf16 lds[2][(BM + BN) * BK];   // 2 x 24 KB

  int tid = threadIdx.x;
  int lane = tid & 63;
  int wv = tid >> 6;   // 0..7

  // staging: A = 1024 chunks of 16B (2/wave), B = 512 chunks (1/wave)
  const __bf16* aptr[2];
  int adst[2];
#pragma unroll
  for (int i = 0; i < 2; ++i) {
    int c = (wv * 2 + i) * 64 + lane;
    int r = c >> 3, kc = c & 7;
    int gr = mt * BM + r;
    int tok = list_tok[lbase + min(gr, cnt - 1)];
    aptr[i] = tok_bf + (size_t)tok * HDIM + (kc ^ (r & 7)) * 8;
    adst[i] = (wv * 2 + i) * 512;
  }
  const __bf16* bptr;
  int bdst;
  {
    int c = wv * 64 + lane;
    int r = c >> 3, kc = c & 7;
    int d = nt * BN + r;
    bptr = w_bf + ((size_t)e * HDIM + d) * HDIM + (kc ^ (r & 7)) * 8;
    bdst = BM * BK + wv * 512;
  }

  int lr = lane & 15;
  int lk = lane >> 4;
  int wr = (wv & 3) * 32;    // 0/32/64/96
  int wc = (wv >> 2) * 32;   // 0/32

  int aoffr[2][2], boffr[2][2];
#pragma unroll
  for (int kk = 0; kk < 2; ++kk) {
#pragma unroll
    for (int m = 0; m < 2; ++m) {
      int r = wr + m * 16 + lr;
      aoffr[kk][m] = r * BK + (((kk * 4 + lk) ^ (r & 7)) * 8);
    }
#pragma unroll
    for (int n = 0; n < 2; ++n) {
      int d = wc + n * 16 + lr;
      boffr[kk][n] = BM * BK + d * BK + (((kk * 4 + lk) ^ (d & 7)) * 8);
    }
  }

  f32x4 acc[2][2] = {};

  // prologue: stage kb=0 into buf 0
#pragma unroll
  for (int i = 0; i < 2; ++i) gload16(aptr[i], &lds[0][adst[i]]);
  gload16(bptr, &lds[0][bdst]);
  __syncthreads();

  int buf = 0;
  for (int kb = 0; kb < HDIM / BK; ++kb) {
    if (kb + 1 < HDIM / BK) {
      int nb = buf ^ 1;
      int ko = (kb + 1) * BK;
#pragma unroll
      for (int i = 0; i < 2; ++i) gload16(aptr[i] + ko, &lds[nb][adst[i]]);
      gload16(bptr + ko, &lds[nb][bdst]);
    }

    bf16x8 af[2][2], bfr[2][2];
#pragma unroll
    for (int kk = 0; kk < 2; ++kk) {
#pragma unroll
      for (int m = 0; m < 2; ++m) af[kk][m] = *(const bf16x8*)(&lds[buf][aoffr[kk][m]]);
#pragma unroll
      for (int n = 0; n < 2; ++n) bfr[kk][n] = *(const bf16x8*)(&lds[buf][boffr[kk][n]]);
    }
#pragma unroll
    for (int kk = 0; kk < 2; ++kk)
#pragma unroll
      for (int m = 0; m < 2; ++m)
#pragma unroll
        for (int n = 0; n < 2; ++n)
          acc[m][n] = __builtin_amdgcn_mfma_f32_16x16x32_bf16(af[kk][m], bfr[kk][n], acc[m][n], 0, 0, 0);

    __syncthreads();   // staged nb complete + all reads of buf done
    buf ^= 1;
  }

  // epilogue: C/D layout col = lane&15, row = (lane>>4)*4 + j
#pragma unroll
  for (int m = 0; m < 2; ++m) {
#pragma unroll
    for (int j = 0; j < 4; ++j) {
      int rloc = wr + m * 16 + lk * 4 + j;
      int grow = mt * BM + rloc;
      if (grow < cnt) {
        int tok = list_tok[lbase + grow];
        float gw = list_w[lbase + grow];
        float* orow = out + (size_t)tok * HDIM + nt * BN + wc;
        const float* brow = expert_b + e * HDIM + nt * BN + wc;
#pragma unroll
        for (int n = 0; n < 2; ++n) {
          int dc = n * 16 + lr;
          float v = acc[m][n][j] + brow[dc];
          atomicAdd(orow + dc, fmaxf(v, 0.f) * gw);
        }
      }
    }
  }
}

extern "C" void kernel_launch(void* const* d_in, const int* in_sizes, int n_in,
                              void* d_out, int out_size, void* d_ws, size_t ws_size,
                              hipStream_t stream) {
  const float* tokens = (const float*)d_in[0];
  const float* gate_w = (const float*)d_in[1];
  const float* expert_w = (const float*)d_in[2];
  const float* expert_b = (const float*)d_in[3];
  float* out = (float*)d_out;

  int* counts = (int*)d_ws;                            // 16
  int* npg = counts + 16;                              // 16 (use 1)
  int* tiles = npg + 16;                               // MAXP*2
  int* tok_idx = tiles + MAXP * 2;                     // 8192
  float* tok_w = (float*)(tok_idx + TOKENS * 2);       // 8192
  int* list_tok = (int*)(tok_w + TOKENS * 2);          // 65536
  float* list_w = (float*)(list_tok + NEXP * TOKENS);  // 65536
  size_t head = (size_t)(list_w + NEXP * TOKENS) - (size_t)d_ws;
  head = (head + 255) & ~(size_t)255;
  __bf16* w_bf = (__bf16*)((char*)d_ws + head);        // 32 MB
  __bf16* tok_bf = w_bf + (size_t)NEXP * HDIM * HDIM;  // 8 MB

  hipMemsetAsync(d_out, 0, (size_t)out_size * sizeof(float), stream);

  cvt_kernel<<<NEXP * HDIM * HDIM / 8 / 256, 256, 0, stream>>>(expert_w, w_bf);
  gate_kernel<<<TOKENS / 4, 256, 0, stream>>>(tokens, gate_w, tok_idx, tok_w, tok_bf);
  build_lists_kernel<<<NEXP, 1024, 0, stream>>>(tok_idx, tok_w, counts, list_tok, list_w);
  plan_kernel<<<1, 64, 0, stream>>>(counts, tiles, npg);

  moe_gemm_kernel<<<MAXT, 512, 0, stream>>>(tok_bf, w_bf, expert_b, counts, tiles, npg,
                                            list_tok, list_w, out);
}